// Round 2
// baseline (790.306 us; speedup 1.0000x reference)
//
#include <hip/hip_runtime.h>

// RelationAwareAttention: B=2,H=8,L=2048,DK=64 (fp32 I/O, bf16 comparison space)
//   s = (Q K^T + tree + leaf) / sqrt(192); s[mask]=-1e9; p=softmax(s); O=pV
// Outputs concatenated: [attn_sum (B,H,L,DK) ; p_attn (B,H,L,L)], fp32.
//
// V2.1 structure: LDS-resident fp16 score tile (16x2048 = 64 KiB, 2 WG/CU),
// 3 barriers total (was 96). Phases:
//   A: QK^T via MFMA -> LDS fp16 (per-wave independent, rotated K prefetch)
//   B: barrier-free stream of tree/leaf/mask (nontemporal, DEPTH-2 named-reg
//      prefetch), s written back to LDS fp16, THREAD-PRIVATE online (m,l);
//      one final 16-lane shuffle merge per row.
//   C1: p = exp(s-m)*linv from LDS -> nontemporal fp32 store; LDS slot
//       overwritten in place with bf16 p~ (thread-local, no hazard).
//   C2: PV MFMA reading A-frags from LDS (XOR-swizzled: ~2-way = free).
// Kills the 512 MiB global score-scratch round-trip; Phase B keeps ~48 KB/CU
// of loads in flight (need ~9.2 KB to saturate HBM at ~375 ns latency).

#define B_   2
#define H_   8
#define L_   2048
#define DK_  64
#define BH_  16
#define M_   16
#define SCALE 0.07216878364870323f   // 1/sqrt(3*64)
#define MASKVAL -65504.0f            // fp16 lowest; exp underflows to 0 like -1e9

typedef __attribute__((ext_vector_type(8))) short    short8;
typedef __attribute__((ext_vector_type(4))) float    f32x4;
typedef __attribute__((ext_vector_type(4))) int      i32x4;
typedef __attribute__((ext_vector_type(4))) _Float16 h16x4;
typedef __attribute__((ext_vector_type(8))) _Float16 h16x8;

__device__ __forceinline__ unsigned short f2bf(float f) {
    union { float f; unsigned int i; } x; x.f = f;
    unsigned int u = x.i;
    return (unsigned short)((u + 0x7fffu + ((u >> 16) & 1u)) >> 16);  // RNE
}
__device__ __forceinline__ short8 pack8f(const float* a) {
    short8 r;
#pragma unroll
    for (int i = 0; i < 8; ++i) r[i] = (short)f2bf(a[i]);
    return r;
}
// LDS byte offset for score element (row, col): row-major [16][2048] fp16,
// XOR-swizzled so PV A-frag reads (16 rows, same col window) hit 8 distinct
// 16B slots (~2-way = free) instead of 16-way bank conflict. XOR only touches
// byte-address bits 4..6, so any 16B-aligned 16B access stays contiguous.
__device__ __forceinline__ int swz(int row, int colByte) {
    return (row * (L_ * 2) + colByte) ^ ((row & 7) << 4);
}

__global__ __launch_bounds__(256)
void raa_fused_kernel(const float* __restrict__ q,
                      const float* __restrict__ k,
                      const float* __restrict__ v,
                      const int*   __restrict__ mask,   // (B,1,L,L)
                      const float* __restrict__ tree,
                      const float* __restrict__ leaf,
                      float*       __restrict__ attn,   // (B,H,L,DK)
                      float*       __restrict__ p)      // (B,H,L,L)
{
    const int t    = threadIdx.x;
    const int wv   = t >> 6;
    const int lane = t & 63;
    const int bh   = blockIdx.x;          // 0..15 (bh%8 -> XCD: 2 bh per XCD)
    const int b    = bh >> 3;
    const int i0   = blockIdx.y * M_;

    __shared__ __align__(16) unsigned short s16[M_ * L_];  // fp16 s, then bf16 p~
    __shared__ float s_m[M_], s_linv[M_];
    char* sb = (char*)s16;

    const int prow = t >> 4;              // stream row owner
    const int pc4  = (t & 15) * 4;

    // ---- depth-2 prefetch of phase-B chunks 0,1 (hidden under phase A) ----
    const size_t bias_row = ((size_t)bh * L_ + i0 + prow) * L_ + pc4;
    const size_t mask_row = ((size_t)b  * L_ + i0 + prow) * L_ + pc4;
    f32x4 tB0 = __builtin_nontemporal_load((const f32x4*)(tree + bias_row));
    f32x4 lB0 = __builtin_nontemporal_load((const f32x4*)(leaf + bias_row));
    i32x4 mB0 = *(const i32x4*)(mask + mask_row);
    f32x4 tB1 = __builtin_nontemporal_load((const f32x4*)(tree + bias_row + 64));
    f32x4 lB1 = __builtin_nontemporal_load((const f32x4*)(leaf + bias_row + 64));
    i32x4 mB1 = *(const i32x4*)(mask + mask_row + 64);

    // ---- Q fragments (A-operand: row m=lane&15, k=(lane>>4)*8..) ----
    const size_t qbase = ((size_t)bh * L_ + i0 + (lane & 15)) * (size_t)DK_
                       + ((lane >> 4) * 8);
    float qf[8], qg[8];
    *(f32x4*)&qf[0] = *(const f32x4*)(q + qbase);
    *(f32x4*)&qf[4] = *(const f32x4*)(q + qbase + 4);
    *(f32x4*)&qg[0] = *(const f32x4*)(q + qbase + 32);
    *(f32x4*)&qg[4] = *(const f32x4*)(q + qbase + 36);
    const short8 aq0 = pack8f(qf), aq1 = pack8f(qg);

    // ================= Phase A: QK^T -> LDS fp16 (no barriers) =================
    const float* kbase = k + (size_t)bh * L_ * DK_ + ((lane >> 4) * 8);
    const int kr = wv * 16 + (lane & 15);          // K row within 64-col chunk
    float kc[16];
    {
        const float* kp = kbase + (size_t)kr * DK_;
        *(f32x4*)&kc[0]  = *(const f32x4*)(kp);
        *(f32x4*)&kc[4]  = *(const f32x4*)(kp + 4);
        *(f32x4*)&kc[8]  = *(const f32x4*)(kp + 32);
        *(f32x4*)&kc[12] = *(const f32x4*)(kp + 36);
    }
    for (int jc = 0; jc < 32; ++jc) {
        float kn[16];
        {   // rotated prefetch of next chunk's K rows (clamped; dup load is L2-hot)
            const int nj = (jc < 31) ? jc + 1 : 31;
            const float* kp = kbase + (size_t)(nj * 64 + kr) * DK_;
            *(f32x4*)&kn[0]  = *(const f32x4*)(kp);
            *(f32x4*)&kn[4]  = *(const f32x4*)(kp + 4);
            *(f32x4*)&kn[8]  = *(const f32x4*)(kp + 32);
            *(f32x4*)&kn[12] = *(const f32x4*)(kp + 36);
        }
        const short8 kb0 = pack8f(&kc[0]);
        const short8 kb1 = pack8f(&kc[8]);
        f32x4 acc = {0.f, 0.f, 0.f, 0.f};
        acc = __builtin_amdgcn_mfma_f32_16x16x32_bf16(aq0, kb0, acc, 0, 0, 0);
        acc = __builtin_amdgcn_mfma_f32_16x16x32_bf16(aq1, kb1, acc, 0, 0, 0);
        const int r0   = (lane >> 4) * 4;          // C: row=(lane>>4)*4+r, col=lane&15
        const int ccol = jc * 64 + wv * 16 + (lane & 15);
#pragma unroll
        for (int r = 0; r < 4; ++r)
            *(_Float16*)(sb + swz(r0 + r, ccol * 2)) = (_Float16)acc[r];
#pragma unroll
        for (int u = 0; u < 16; ++u) kc[u] = kn[u];
    }
    __syncthreads();

    // ====== Phase B: stream bias+mask, finalize s in LDS, private (m,l) ======
    float m_loc = -INFINITY, l_loc = 0.f;
    auto procB = [&](int jc, f32x4 t4, f32x4 l4, i32x4 mk) {
        const int ad = swz(prow, (jc * 64 + pc4) * 2);
        h16x4 qh = *(h16x4*)(sb + ad);
        float su[4];
#pragma unroll
        for (int e = 0; e < 4; ++e) {
            float s = ((float)qh[e] + t4[e] + l4[e]) * SCALE;
            s = mk[e] ? MASKVAL : s;
            _Float16 hs = (_Float16)s;      // round once; use rounded value for
            qh[e] = hs;                     // l so p sums to exactly 1
            su[e] = (float)hs;
        }
        *(h16x4*)(sb + ad) = qh;
        const float cmax = fmaxf(fmaxf(su[0], su[1]), fmaxf(su[2], su[3]));
        if (cmax > m_loc) { l_loc *= __expf(m_loc - cmax); m_loc = cmax; }
        l_loc += __expf(su[0] - m_loc) + __expf(su[1] - m_loc)
               + __expf(su[2] - m_loc) + __expf(su[3] - m_loc);
    };
    for (int jc = 0; jc < 32; jc += 2) {
        {   // chunk jc (buffer 0); refill with chunk jc+2
            const f32x4 t4 = tB0, l4 = lB0; const i32x4 mk = mB0;
            const int nj = (jc + 2 < 32) ? jc + 2 : jc;
            const size_t off = bias_row + (size_t)nj * 64;
            tB0 = __builtin_nontemporal_load((const f32x4*)(tree + off));
            lB0 = __builtin_nontemporal_load((const f32x4*)(leaf + off));
            mB0 = *(const i32x4*)(mask + mask_row + (size_t)nj * 64);
            procB(jc, t4, l4, mk);
        }
        {   // chunk jc+1 (buffer 1); refill with chunk jc+3
            const f32x4 t4 = tB1, l4 = lB1; const i32x4 mk = mB1;
            const int nj = (jc + 3 < 32) ? jc + 3 : jc + 1;
            const size_t off = bias_row + (size_t)nj * 64;
            tB1 = __builtin_nontemporal_load((const f32x4*)(tree + off));
            lB1 = __builtin_nontemporal_load((const f32x4*)(leaf + off));
            mB1 = *(const i32x4*)(mask + mask_row + (size_t)nj * 64);
            procB(jc + 1, t4, l4, mk);
        }
    }
    // merge (m,l) across the 16 lanes of each row (lanes are contiguous)
#pragma unroll
    for (int d = 1; d < 16; d <<= 1) {
        const float mo = __shfl_xor(m_loc, d);
        const float lo = __shfl_xor(l_loc, d);
        const float mn = fmaxf(m_loc, mo);
        l_loc = l_loc * __expf(m_loc - mn) + lo * __expf(mo - mn);
        m_loc = mn;
    }
    if ((t & 15) == 0) { s_m[prow] = m_loc; s_linv[prow] = 1.f / l_loc; }
    __syncthreads();

    // ====== Phase C1: p = exp(s-m)*linv -> global; LDS := bf16 p~ in place ======
    {
        const float mrow = s_m[prow], li = s_linv[prow];
        const size_t prowoff = ((size_t)bh * L_ + i0 + prow) * L_;
        const int c8 = (t & 15) * 8;
        for (int ch = 0; ch < 16; ++ch) {
            const int col = ch * 128 + c8;
            const int ad  = swz(prow, col * 2);
            const h16x8 hv = *(const h16x8*)(sb + ad);
            float pv[8];
#pragma unroll
            for (int e = 0; e < 8; ++e) pv[e] = __expf((float)hv[e] - mrow) * li;
            f32x4 o0 = { pv[0], pv[1], pv[2], pv[3] };
            f32x4 o1 = { pv[4], pv[5], pv[6], pv[7] };
            __builtin_nontemporal_store(o0, (f32x4*)(p + prowoff + col));
            __builtin_nontemporal_store(o1, (f32x4*)(p + prowoff + col + 4));
            *(short8*)(sb + ad) = pack8f(pv);   // own slot: no cross-thread hazard
        }
    }
    __syncthreads();

    // ================= Phase C2: O = p~ V via MFMA (no barriers) =================
    f32x4 oacc = {0.f, 0.f, 0.f, 0.f};
    const float* vb = v + (size_t)bh * L_ * DK_ + wv * 16 + (lane & 15);
#pragma unroll 2
    for (int ch = 0; ch < 16; ++ch) {
#pragma unroll
        for (int kk = 0; kk < 4; ++kk) {
            const int jb = ch * 128 + kk * 32 + (lane >> 4) * 8;
            const short8 af = *(const short8*)(sb + swz(lane & 15, jb * 2));
            const float* vp = vb + (size_t)jb * DK_;
            float vf[8];
#pragma unroll
            for (int u = 0; u < 8; ++u) vf[u] = vp[(size_t)u * DK_];  // L2-hot
            const short8 bfr = pack8f(vf);
            oacc = __builtin_amdgcn_mfma_f32_16x16x32_bf16(af, bfr, oacc, 0, 0, 0);
        }
    }
    {   // epilogue: C-layout -> attn_sum (fp32)
        const int r0  = (lane >> 4) * 4;
        const int col = wv * 16 + (lane & 15);
#pragma unroll
        for (int r = 0; r < 4; ++r)
            attn[((size_t)bh * L_ + i0 + r0 + r) * DK_ + col] = oacc[r];
    }
}

extern "C" void kernel_launch(void* const* d_in, const int* in_sizes, int n_in,
                              void* d_out, int out_size, void* d_ws, size_t ws_size,
                              hipStream_t stream) {
    const float* q    = (const float*)d_in[0];
    const float* k    = (const float*)d_in[1];
    const float* v    = (const float*)d_in[2];
    const int*   mask = (const int*)d_in[3];
    const float* tree = (const float*)d_in[4];
    const float* leaf = (const float*)d_in[5];

    float* attn = (float*)d_out;
    float* p    = attn + (size_t)B_ * H_ * L_ * DK_;  // + 2,097,152 floats

    dim3 grid(BH_, L_ / M_);   // (16, 128)
    raa_fused_kernel<<<grid, 256, 0, stream>>>(q, k, v, mask, tree, leaf, attn, p);
}